// Round 1
// baseline (495.870 us; speedup 1.0000x reference)
//
#include <hip/hip_runtime.h>

#define B 16
#define C 256
#define SPATIAL 4096   // 64*64 spatial sites per (b,c); each site is one float4 (4 comps)

// ---------------- Kernel 1: global spatial max-pool per (b,c,comp) ----------
__global__ __launch_bounds__(256) void pool_kernel(const float4* __restrict__ x4,
                                                   float4* __restrict__ pooled4) {
    const int bc = blockIdx.x;                     // 0 .. B*C-1
    const float4* p = x4 + (size_t)bc * SPATIAL;
    const int tid = threadIdx.x;

    float4 m = p[tid];
    #pragma unroll
    for (int s = tid + 256; s < SPATIAL; s += 256) {
        float4 v = p[s];
        m.x = fmaxf(m.x, v.x);
        m.y = fmaxf(m.y, v.y);
        m.z = fmaxf(m.z, v.z);
        m.w = fmaxf(m.w, v.w);
    }

    // wave(64)-level reduce
    #pragma unroll
    for (int off = 32; off > 0; off >>= 1) {
        m.x = fmaxf(m.x, __shfl_down(m.x, off));
        m.y = fmaxf(m.y, __shfl_down(m.y, off));
        m.z = fmaxf(m.z, __shfl_down(m.z, off));
        m.w = fmaxf(m.w, __shfl_down(m.w, off));
    }

    __shared__ float4 lm[4];
    const int lane = tid & 63, wid = tid >> 6;
    if (lane == 0) lm[wid] = m;
    __syncthreads();
    if (tid == 0) {
        float4 r = lm[0];
        #pragma unroll
        for (int w = 1; w < 4; ++w) {
            r.x = fmaxf(r.x, lm[w].x);
            r.y = fmaxf(r.y, lm[w].y);
            r.z = fmaxf(r.z, lm[w].z);
            r.w = fmaxf(r.w, lm[w].w);
        }
        pooled4[bc] = r;
    }
}

// ---------------- Kernel 2: squeeze-excite MLP → per-(b,c) float4 scale -----
// comp_w: (4,1,C)   -> comp_w[c*C + i]
// comp_b: (4,1)     -> comp_b[c]
// exc_w : (4,C,1)   -> exc_w[c*C + o]
// exc_b : (4,C)     -> exc_b[c*C + o]
__global__ __launch_bounds__(256) void scale_kernel(const float4* __restrict__ pooled4,
                                                    const float* __restrict__ comp_w,
                                                    const float* __restrict__ comp_b,
                                                    const float* __restrict__ exc_w,
                                                    const float* __restrict__ exc_b,
                                                    float4* __restrict__ scale4) {
    const int b = blockIdx.x;
    const int o = threadIdx.x;                     // doubles as input-channel index i

    float4 p = pooled4[b * C + o];
    float4 prod;
    prod.x = p.x * comp_w[0 * C + o];
    prod.y = p.y * comp_w[1 * C + o];
    prod.z = p.z * comp_w[2 * C + o];
    prod.w = p.w * comp_w[3 * C + o];

    #pragma unroll
    for (int off = 32; off > 0; off >>= 1) {
        prod.x += __shfl_down(prod.x, off);
        prod.y += __shfl_down(prod.y, off);
        prod.z += __shfl_down(prod.z, off);
        prod.w += __shfl_down(prod.w, off);
    }

    __shared__ float4 lsum[4];
    const int lane = o & 63, wid = o >> 6;
    if (lane == 0) lsum[wid] = prod;
    __syncthreads();

    // every thread forms the full sum (redundant, but uniform & cheap)
    float r  = lsum[0].x + lsum[1].x + lsum[2].x + lsum[3].x + comp_b[0];
    float xc = lsum[0].y + lsum[1].y + lsum[2].y + lsum[3].y + comp_b[1];
    float yc = lsum[0].z + lsum[1].z + lsum[2].z + lsum[3].z + comp_b[2];
    float zc = lsum[0].w + lsum[1].w + lsum[2].w + lsum[3].w + comp_b[3];

    // Hamilton-style combine #1  (Cout = 1)
    const float u0 = r + xc + yc + zc;
    const float u1 = xc - r - zc + yc;
    const float u2 = yc + zc - r - xc;
    const float u3 = zc - yc + xc - r;

    // excite linear per output channel o (Cin = 1)
    const float c0 = u0 * exc_w[0 * C + o] + exc_b[0 * C + o];
    const float c1 = u1 * exc_w[1 * C + o] + exc_b[1 * C + o];
    const float c2 = u2 * exc_w[2 * C + o] + exc_b[2 * C + o];
    const float c3 = u3 * exc_w[3 * C + o] + exc_b[3 * C + o];

    // Hamilton-style combine #2
    float4 s;
    s.x = c0 + c1 + c2 + c3;
    s.y = c1 - c0 - c3 + c2;
    s.z = c2 + c3 - c0 - c1;
    s.w = c3 - c2 + c1 - c0;
    scale4[b * C + o] = s;
}

// ---------------- Kernel 3: out = x * scale (broadcast over spatial) --------
__global__ __launch_bounds__(256) void mul_kernel(const float4* __restrict__ x4,
                                                  const float4* __restrict__ scale4,
                                                  float4* __restrict__ out4) {
    const int bc = blockIdx.x;
    const float4 s = scale4[bc];
    const float4* xp = x4 + (size_t)bc * SPATIAL;
    float4* op = out4 + (size_t)bc * SPATIAL;
    #pragma unroll 4
    for (int i = threadIdx.x; i < SPATIAL; i += 256) {
        float4 v = xp[i];
        v.x *= s.x;
        v.y *= s.y;
        v.z *= s.z;
        v.w *= s.w;
        op[i] = v;
    }
}

extern "C" void kernel_launch(void* const* d_in, const int* in_sizes, int n_in,
                              void* d_out, int out_size, void* d_ws, size_t ws_size,
                              hipStream_t stream) {
    const float4* x4     = (const float4*)d_in[0];
    const float*  comp_w = (const float*)d_in[1];
    const float*  comp_b = (const float*)d_in[2];
    const float*  exc_w  = (const float*)d_in[3];
    const float*  exc_b  = (const float*)d_in[4];
    float4* out4 = (float4*)d_out;

    float4* pooled4 = (float4*)d_ws;          // B*C float4 = 64 KiB
    float4* scale4  = pooled4 + B * C;        // B*C float4 = 64 KiB

    pool_kernel<<<B * C, 256, 0, stream>>>(x4, pooled4);
    scale_kernel<<<B, 256, 0, stream>>>(pooled4, comp_w, comp_b, exc_w, exc_b, scale4);
    mul_kernel<<<B * C, 256, 0, stream>>>(x4, scale4, out4);
}

// Round 2
// 482.192 us; speedup vs baseline: 1.0284x; 1.0284x over previous
//
#include <hip/hip_runtime.h>

#define B 16
#define C 256
#define SPATIAL 4096   // 64*64 spatial sites per (b,c); each site is one float4 (4 comps)

typedef float vf4 __attribute__((ext_vector_type(4)));

// ---------------- Kernel 1: global spatial max-pool per (b,c,comp) ----------
__global__ __launch_bounds__(256) void pool_kernel(const float4* __restrict__ x4,
                                                   float4* __restrict__ pooled4) {
    const int bc = blockIdx.x;                     // 0 .. B*C-1
    const float4* p = x4 + (size_t)bc * SPATIAL;
    const int tid = threadIdx.x;

    float4 m = p[tid];
    #pragma unroll
    for (int s = tid + 256; s < SPATIAL; s += 256) {
        float4 v = p[s];
        m.x = fmaxf(m.x, v.x);
        m.y = fmaxf(m.y, v.y);
        m.z = fmaxf(m.z, v.z);
        m.w = fmaxf(m.w, v.w);
    }

    // wave(64)-level reduce
    #pragma unroll
    for (int off = 32; off > 0; off >>= 1) {
        m.x = fmaxf(m.x, __shfl_down(m.x, off));
        m.y = fmaxf(m.y, __shfl_down(m.y, off));
        m.z = fmaxf(m.z, __shfl_down(m.z, off));
        m.w = fmaxf(m.w, __shfl_down(m.w, off));
    }

    __shared__ float4 lm[4];
    const int lane = tid & 63, wid = tid >> 6;
    if (lane == 0) lm[wid] = m;
    __syncthreads();
    if (tid == 0) {
        float4 r = lm[0];
        #pragma unroll
        for (int w = 1; w < 4; ++w) {
            r.x = fmaxf(r.x, lm[w].x);
            r.y = fmaxf(r.y, lm[w].y);
            r.z = fmaxf(r.z, lm[w].z);
            r.w = fmaxf(r.w, lm[w].w);
        }
        pooled4[bc] = r;
    }
}

// ------- Kernel 2: fused scale-MLP (redundant per block) + broadcast mul ----
// comp_w: (4,1,C) -> comp_w[comp*C + i]
// comp_b: (4,1)   -> comp_b[comp]
// exc_w : (4,C,1) -> exc_w[comp*C + o]
// exc_b : (4,C)   -> exc_b[comp*C + o]
// Blocks run in REVERSE bc order so the mul pass re-reads the tail of x
// (most recently touched by pool_kernel -> L3-resident) first.
__global__ __launch_bounds__(256) void scale_mul_kernel(const float4* __restrict__ x4,
                                                        const float4* __restrict__ pooled4,
                                                        const float* __restrict__ comp_w,
                                                        const float* __restrict__ comp_b,
                                                        const float* __restrict__ exc_w,
                                                        const float* __restrict__ exc_b,
                                                        float4* __restrict__ out4) {
    const int bc  = (B * C - 1) - blockIdx.x;      // reversed traversal
    const int b   = bc >> 8;                       // bc / C
    const int c   = bc & (C - 1);                  // bc % C
    const int tid = threadIdx.x;

    // ---- squeeze: dot(pooled[b,:,:], comp_w) over 256 channels (block reduce)
    float4 p = pooled4[b * C + tid];               // tid == input channel i
    float4 prod;
    prod.x = p.x * comp_w[0 * C + tid];
    prod.y = p.y * comp_w[1 * C + tid];
    prod.z = p.z * comp_w[2 * C + tid];
    prod.w = p.w * comp_w[3 * C + tid];

    #pragma unroll
    for (int off = 32; off > 0; off >>= 1) {
        prod.x += __shfl_down(prod.x, off);
        prod.y += __shfl_down(prod.y, off);
        prod.z += __shfl_down(prod.z, off);
        prod.w += __shfl_down(prod.w, off);
    }

    __shared__ float4 lsum[4];
    const int lane = tid & 63, wid = tid >> 6;
    if (lane == 0) lsum[wid] = prod;
    __syncthreads();

    // every thread forms the (wave-uniform) sums — cheap, no extra barrier
    const float r  = lsum[0].x + lsum[1].x + lsum[2].x + lsum[3].x + comp_b[0];
    const float xc = lsum[0].y + lsum[1].y + lsum[2].y + lsum[3].y + comp_b[1];
    const float yc = lsum[0].z + lsum[1].z + lsum[2].z + lsum[3].z + comp_b[2];
    const float zc = lsum[0].w + lsum[1].w + lsum[2].w + lsum[3].w + comp_b[3];

    // Hamilton-style combine #1 (Cout = 1)
    const float u0 = r + xc + yc + zc;
    const float u1 = xc - r - zc + yc;
    const float u2 = yc + zc - r - xc;
    const float u3 = zc - yc + xc - r;

    // excite linear for this block's output channel c (Cin = 1); c is uniform
    const float c0 = u0 * exc_w[0 * C + c] + exc_b[0 * C + c];
    const float c1 = u1 * exc_w[1 * C + c] + exc_b[1 * C + c];
    const float c2 = u2 * exc_w[2 * C + c] + exc_b[2 * C + c];
    const float c3 = u3 * exc_w[3 * C + c] + exc_b[3 * C + c];

    // Hamilton-style combine #2 -> per-(b,c) quaternion scale
    vf4 s;
    s.x = c0 + c1 + c2 + c3;
    s.y = c1 - c0 - c3 + c2;
    s.z = c2 + c3 - c0 - c1;
    s.w = c3 - c2 + c1 - c0;

    // ---- broadcast multiply over the 4096-site slice; NT stores keep L3 for x
    const vf4* xp = (const vf4*)(x4 + (size_t)bc * SPATIAL);
    vf4*       op = (vf4*)(out4 + (size_t)bc * SPATIAL);
    #pragma unroll 4
    for (int i = tid; i < SPATIAL; i += 256) {
        vf4 v = xp[i];
        v *= s;
        __builtin_nontemporal_store(v, op + i);
    }
}

extern "C" void kernel_launch(void* const* d_in, const int* in_sizes, int n_in,
                              void* d_out, int out_size, void* d_ws, size_t ws_size,
                              hipStream_t stream) {
    const float4* x4     = (const float4*)d_in[0];
    const float*  comp_w = (const float*)d_in[1];
    const float*  comp_b = (const float*)d_in[2];
    const float*  exc_w  = (const float*)d_in[3];
    const float*  exc_b  = (const float*)d_in[4];
    float4* out4 = (float4*)d_out;

    float4* pooled4 = (float4*)d_ws;          // B*C float4 = 64 KiB scratch

    pool_kernel<<<B * C, 256, 0, stream>>>(x4, pooled4);
    scale_mul_kernel<<<B * C, 256, 0, stream>>>(x4, pooled4, comp_w, comp_b,
                                                exc_w, exc_b, out4);
}